// Round 8
// baseline (114.637 us; speedup 1.0000x reference)
//
#include <hip/hip_runtime.h>

// Quantum conv circuit, 16 qubits, batch 16.
// Round 8: 3 dispatches. P3 eliminated via sigma1 factorization:
//   sigma1 = s1b (pairs 15->14,13->12,5->4,3->2,1->0; ctrl mask 0xA02A)
//          * s1a (pairs 11->10,9->8,7->6;           ctrl mask 0x0A80)  [disjoint, commute]
//   P4 gathers through s1b, applies L1d1 g6..g10 in-tile (its inner set contains them),
//   evaluates D1 at the s1b-permuted index (XOR-linear), then folds s1a into the next
//   LDS-read permutation. k_setup eliminated: per-block double-trig table prologue (r6-verified).
// 512 blocks x 512 threads, 4 amps/thread, 11-bit tiles. st = float2[16][65536] at d_ws.
// Bit convention: wire w <-> flat-index bit p = 15-w.
// Gate index: L1d0(p)=15-p, L1d1(p)=16+(15-p), L2d0(p)=32+(15-p)/2, L2d1(p)=40+(15-p)/2,
//             L3d0(p)=48+(15-p)/4, L3d1(p)=52+(15-p)/4, L4d0(p)=56+(15-p)/8, L4d1(p)=58+(15-p)/8.

#define DEV __device__ __forceinline__
#define TB(i) (tbs + (i)*8)

__device__ static const unsigned char G_CP[60] = {
  15,14,13,12,11,10,9,8,7,6,5,4,3,2,1,0,
  15,14,13,12,11,10,9,8,7,6,5,4,3,2,1,0,
  15,13,11,9,7,5,3,1,
  15,13,11,9,7,5,3,1,
  15,11,7,3,
  15,11,7,3,
  15,7,
  15,7
};
__device__ static const unsigned char G_CQ[60] = {
  14,13,12,11,10,9,8,7,6,5,4,3,2,1,0,15,
  14,13,12,11,10,9,8,7,6,5,4,3,2,1,0,15,
  13,11,9,7,5,3,1,15,
  13,11,9,7,5,3,1,15,
  11,7,3,15,
  11,7,3,15,
  7,15,
  7,15
};

DEV float2 F2(float x, float y){ float2 r; r.x = x; r.y = y; return r; }
DEV float2 cmulf(float2 a, float2 b){ return F2(a.x*b.x - a.y*b.y, a.x*b.y + a.y*b.x); }
// XOR bank swizzle on float2 slot index, 2048 slots (32 banks = 16 float2 columns).
DEV int swz(int j){ return j ^ ((j>>4)&15) ^ ((j>>8)&15); }

// slot s (2 bits) -> inner bits A (s bit0), B (s bit1); t's 9 bits fill the rest ascending.
template<int A,int B>
DEV int mapj(int t, int s){
  int j = ((s&1)<<A) | (((s>>1)&1)<<B);
  int ti = 0;
  #pragma unroll
  for (int b=0;b<11;b++){
    if (b!=A && b!=B){ j |= ((t>>ti)&1)<<b; ti++; }
  }
  return j;
}

// 2x2 unitary on slot bit SB of a[4].
template<int SB>
DEV void gate4(float2* a, const float* g){
  float u00r=g[0],u00i=g[1],u01r=g[2],u01i=g[3],u10r=g[4],u10i=g[5],u11r=g[6],u11i=g[7];
  #pragma unroll
  for (int m=0;m<2;m++){
    int i0 = (SB==0) ? (m<<1) : m;
    int i1 = i0 | (1<<SB);
    float2 x0=a[i0], x1=a[i1];
    a[i0] = F2(u00r*x0.x - u00i*x0.y + u01r*x1.x - u01i*x1.y,
               u00r*x0.y + u00i*x0.x + u01r*x1.y + u01i*x1.x);
    a[i1] = F2(u10r*x0.x - u10i*x0.y + u11r*x1.x - u11i*x1.y,
               u10r*x0.y + u10i*x0.x + u11r*x1.y + u11i*x1.x);
  }
}

// RZZ round, couplings [C0,C0+N). Ib = global 16-bit index with the two reg bits zeroed.
template<int C0,int N,unsigned M0,unsigned M1>
DEV void diag4(float2* a, const float* tbs, unsigned Ib){
  const unsigned regmask = M0|M1;
  float2 F0 = F2(1.f, 0.f);
  #pragma unroll
  for (int k=0;k<N;k++){
    const int p = G_CP[C0+k], q = G_CQ[C0+k];
    if ( !(((1u<<p)|(1u<<q)) & regmask) ){
      float c = tbs[480 + 2*(C0+k)], s = tbs[481 + 2*(C0+k)];
      unsigned x = ((Ib>>p) ^ (Ib>>q)) & 1u;
      F0 = cmulf(F0, F2(c, x ? s : -s));
    }
  }
  #pragma unroll
  for (int r=0;r<4;r++){
    unsigned Ir = Ib ^ ((r&1)?M0:0u) ^ ((r&2)?M1:0u);
    float2 ph = F0;
    #pragma unroll
    for (int k=0;k<N;k++){
      const int p = G_CP[C0+k], q = G_CQ[C0+k];
      if ( ((1u<<p)|(1u<<q)) & regmask ){
        float c = tbs[480 + 2*(C0+k)], s = tbs[481 + 2*(C0+k)];
        unsigned x = ((Ir>>p) ^ (Ir>>q)) & 1u;
        ph = cmulf(ph, F2(c, x ? s : -s));
      }
    }
    a[r] = cmulf(a[r], ph);
  }
}

// ---- global index maps ----
// P1: inner j0..10 = g0..g10, outer o = g11..15
DEV unsigned Ia(int j, int o){ return (unsigned)(j | (o<<11)); }
// P2: inner (j0..5)=(g0..g5), (j6..10)=(g11..15); outer o = g6..g10
DEV unsigned Ib2(int j, int o){ return (unsigned)((j&63) | (o<<6) | ((j>>6)<<11)); }
// P4: inner j0..10 -> g{1,3,5,6,7,8,9,10,11,13,15}; outer o0..4 -> g{0,2,4,12,14}
DEV unsigned Ic(int j, int o){
  return (unsigned)( ((j&1)<<1) | (((j>>1)&1)<<3) | (((j>>2)&1)<<5)
       | (((j>>3)&63)<<6) | (((j>>9)&1)<<13) | (((j>>10)&1)<<15)
       | (o&1) | (((o>>1)&1)<<2) | (((o>>2)&1)<<4) | (((o>>3)&1)<<12) | (((o>>4)&1)<<14) );
}
// sigma1b on global index (controls 15,13,5,3,1 -> targets 14,12,4,2,0); XOR-linear involution.
DEV unsigned s1b(unsigned I){ return I ^ ((I & 0xA02Au) >> 1); }
// sigma1a folded into LDS read (j-space): (j8->j7)=(g11->g10), (j6->j5)=(g9->g8), (j4->j3)=(g7->g6)
DEV int s1aperm(int j){ return j ^ (((j>>8)&1)<<7) ^ (((j>>6)&1)<<5) ^ (((j>>4)&1)<<3); }
// sigma2 remainder: (g11->g9),(g7->g5),(g3->g1) = (j8->j6),(j4->j2),(j1->j0)
DEV int s2perm(int j){ return j ^ (((j>>8)&1)<<6) ^ (((j>>4)&1)<<2) ^ (((j>>1)&1)<<0); }
// sigma3: (g15->g11),(g7->g3) = (j10->j8),(j4->j1)
DEV int s3perm(int j){ return j ^ (((j>>10)&1)<<8) ^ (((j>>4)&1)<<1); }

// ---- per-block gate-table prologue (double precision; r6-verified numerics) ----
DEV void build_tbl(int t, const float* __restrict__ p0, const float* __restrict__ p1,
                   const float* __restrict__ p2, const float* __restrict__ p3,
                   float* tbs){
  if (t < 60){
    int g = t;
    int d, j, n; const float* P;
    if (g < 32)      { n=16; d=(g>>4)&1; j=g&15; P=p0; }
    else if (g < 48) { n=8;  d=(g>>3)&1; j=g&7;  P=p1; }
    else if (g < 56) { n=4;  d=(g>>2)&1; j=g&3;  P=p2; }
    else             { n=2;  d=(g>>1)&1; j=g&1;  P=p3; }
    int base = 4*j + 4*n*d;
    double th0 = P[base+0], th1 = P[base+1], th2 = P[base+2], th3 = P[base+3];
    double c0 = cos(th0*0.5), s0 = sin(th0*0.5);
    double ca = cos(th1*0.5), sa = sin(th1*0.5);
    double c2 = cos(th2*0.5), s2 = sin(th2*0.5);
    double B00r =  ca*c0, B00i = -sa*c0;
    double B01r = -sa*s0, B01i = -ca*s0;
    double B10r =  sa*s0, B10i = -ca*s0;
    double B11r =  ca*c0, B11i =  sa*c0;
    float* oo = tbs + g*8;
    oo[0]=(float)(c2*B00r + s2*B10i); oo[1]=(float)(c2*B00i - s2*B10r);
    oo[2]=(float)(c2*B01r + s2*B11i); oo[3]=(float)(c2*B01i - s2*B11r);
    oo[4]=(float)(s2*B00i + c2*B10r); oo[5]=(float)(-s2*B00r + c2*B10i);
    oo[6]=(float)(s2*B01i + c2*B11r); oo[7]=(float)(-s2*B01r + c2*B11i);
    tbs[480 + 2*g] = (float)cos(th3*0.5);
    tbs[481 + 2*g] = (float)sin(th3*0.5);
  }
}

// ======== pass 1: L1d0 g0..g10. inner = g0..10, outer = g11..15 ========
__global__ __launch_bounds__(512, 4)
void k_p1(const float* __restrict__ xre, const float* __restrict__ xim,
          const float* __restrict__ p0, const float* __restrict__ p1,
          const float* __restrict__ p2, const float* __restrict__ p3,
          float2* __restrict__ st, float* __restrict__ out){
  const int t = threadIdx.x;
  const int batch = blockIdx.x >> 5, o = blockIdx.x & 31;
  const unsigned hi = ((unsigned)batch<<16) | ((unsigned)o<<11);
  __shared__ float2 lds[2][2048];
  __shared__ float tbs[600];
  float2 a[4];
  if (blockIdx.x == 0 && t < 16) out[t] = 0.f;   // visible to P4's atomicAdds (stream order)
  build_tbl(t, p0, p1, p2, p3, tbs);
  __syncthreads();
  { // S1: map(0,1); j = s | (t<<2): float4 loads
    unsigned base = hi | ((unsigned)t<<2);
    float4 re = *(const float4*)(xre + base);
    float4 im = *(const float4*)(xim + base);
    a[0]=F2(re.x,im.x); a[1]=F2(re.y,im.y); a[2]=F2(re.z,im.z); a[3]=F2(re.w,im.w);
  }
  gate4<0>(a, TB(15)); gate4<1>(a, TB(14));                   // g0,g1
  #pragma unroll
  for (int s=0;s<4;s++) lds[0][swz(mapj<0,1>(t,s))] = a[s];
  __syncthreads();
  #pragma unroll
  for (int s=0;s<4;s++) a[s] = lds[0][swz(mapj<2,3>(t,s))];
  gate4<0>(a, TB(13)); gate4<1>(a, TB(12));                   // g2,g3
  #pragma unroll
  for (int s=0;s<4;s++) lds[1][swz(mapj<2,3>(t,s))] = a[s];
  __syncthreads();
  #pragma unroll
  for (int s=0;s<4;s++) a[s] = lds[1][swz(mapj<4,5>(t,s))];
  gate4<0>(a, TB(11)); gate4<1>(a, TB(10));                   // g4,g5
  #pragma unroll
  for (int s=0;s<4;s++) lds[0][swz(mapj<4,5>(t,s))] = a[s];
  __syncthreads();
  #pragma unroll
  for (int s=0;s<4;s++) a[s] = lds[0][swz(mapj<6,7>(t,s))];
  gate4<0>(a, TB(9)); gate4<1>(a, TB(8));                     // g6,g7
  #pragma unroll
  for (int s=0;s<4;s++) lds[1][swz(mapj<6,7>(t,s))] = a[s];
  __syncthreads();
  #pragma unroll
  for (int s=0;s<4;s++) a[s] = lds[1][swz(mapj<8,9>(t,s))];
  gate4<0>(a, TB(7)); gate4<1>(a, TB(6));                     // g8,g9
  #pragma unroll
  for (int s=0;s<4;s++) lds[0][swz(mapj<8,9>(t,s))] = a[s];
  __syncthreads();
  #pragma unroll
  for (int s=0;s<4;s++) a[s] = lds[0][swz(mapj<0,10>(t,s))];
  gate4<1>(a, TB(5));                                         // g10 (slot bit 1)
  #pragma unroll
  for (int s=0;s<4;s++) st[hi | (unsigned)mapj<0,10>(t,s)] = a[s];
}

// ======== pass 2: L1d0 g11..15, D0, L1d1 {g0..g5, g11..15}. outer = g6..g10 ========
__global__ __launch_bounds__(512, 4)
void k_p2(const float* __restrict__ p0, const float* __restrict__ p1,
          const float* __restrict__ p2, const float* __restrict__ p3,
          float2* __restrict__ st){
  const int t = threadIdx.x;
  const int batch = blockIdx.x >> 5, o = blockIdx.x & 31;
  const unsigned bb = (unsigned)batch<<16;
  __shared__ float2 lds[2][2048];
  __shared__ float tbs[600];
  float2 a[4];
  build_tbl(t, p0, p1, p2, p3, tbs);
  __syncthreads();
  // U1: map(10,9) = (g15,g14)
  #pragma unroll
  for (int s=0;s<4;s++) a[s] = st[bb | Ib2(mapj<10,9>(t,s), o)];
  gate4<0>(a, TB(0)); gate4<1>(a, TB(1));                     // L1d0 g15,g14
  #pragma unroll
  for (int s=0;s<4;s++) lds[0][swz(mapj<10,9>(t,s))] = a[s];
  __syncthreads();
  // U2: map(8,7) = (g13,g12)
  #pragma unroll
  for (int s=0;s<4;s++) a[s] = lds[0][swz(mapj<8,7>(t,s))];
  gate4<0>(a, TB(2)); gate4<1>(a, TB(3));                     // L1d0 g13,g12
  #pragma unroll
  for (int s=0;s<4;s++) lds[1][swz(mapj<8,7>(t,s))] = a[s];
  __syncthreads();
  // U3: map(6,5) = (g11,g5)
  #pragma unroll
  for (int s=0;s<4;s++) a[s] = lds[1][swz(mapj<6,5>(t,s))];
  gate4<0>(a, TB(4));                                         // L1d0 g11 -> L1d0 done
  diag4<0,16, (1u<<11),(1u<<5)>(a, tbs, Ib2(mapj<6,5>(t,0), o));// D0
  gate4<0>(a, TB(20)); gate4<1>(a, TB(26));                   // L1d1 g11, g5
  #pragma unroll
  for (int s=0;s<4;s++) lds[0][swz(mapj<6,5>(t,s))] = a[s];
  __syncthreads();
  // U4: map(7,8) = (g12,g13)
  #pragma unroll
  for (int s=0;s<4;s++) a[s] = lds[0][swz(mapj<7,8>(t,s))];
  gate4<0>(a, TB(19)); gate4<1>(a, TB(18));                   // L1d1 g12,g13
  #pragma unroll
  for (int s=0;s<4;s++) lds[1][swz(mapj<7,8>(t,s))] = a[s];
  __syncthreads();
  // U5: map(9,10) = (g14,g15)
  #pragma unroll
  for (int s=0;s<4;s++) a[s] = lds[1][swz(mapj<9,10>(t,s))];
  gate4<0>(a, TB(17)); gate4<1>(a, TB(16));                   // L1d1 g14,g15
  #pragma unroll
  for (int s=0;s<4;s++) lds[0][swz(mapj<9,10>(t,s))] = a[s];
  __syncthreads();
  // U6: map(0,1) = (g0,g1)
  #pragma unroll
  for (int s=0;s<4;s++) a[s] = lds[0][swz(mapj<0,1>(t,s))];
  gate4<0>(a, TB(31)); gate4<1>(a, TB(30));                   // L1d1 g0,g1
  #pragma unroll
  for (int s=0;s<4;s++) lds[1][swz(mapj<0,1>(t,s))] = a[s];
  __syncthreads();
  // U7: map(2,3) = (g2,g3)
  #pragma unroll
  for (int s=0;s<4;s++) a[s] = lds[1][swz(mapj<2,3>(t,s))];
  gate4<0>(a, TB(29)); gate4<1>(a, TB(28));                   // L1d1 g2,g3
  #pragma unroll
  for (int s=0;s<4;s++) lds[0][swz(mapj<2,3>(t,s))] = a[s];
  __syncthreads();
  // U8: map(4,10) = (g4, spare)
  #pragma unroll
  for (int s=0;s<4;s++) a[s] = lds[0][swz(mapj<4,10>(t,s))];
  gate4<0>(a, TB(27));                                        // L1d1 g4
  #pragma unroll
  for (int s=0;s<4;s++) st[bb | Ib2(mapj<4,10>(t,s), o)] = a[s];
}

// ======== pass 4: s1b-gather, L1d1 g6..10, D1, s1a, L2..L4, measure ========
// inner j0..10 -> g{1,3,5,6,7,8,9,10,11,13,15}; outer o0..4 -> g{0,2,4,12,14}
__global__ __launch_bounds__(512, 4)
void k_p4(const float* __restrict__ p0, const float* __restrict__ p1,
          const float* __restrict__ p2, const float* __restrict__ p3,
          float2* __restrict__ st, float* __restrict__ out){
  const int t = threadIdx.x;
  const int batch = blockIdx.x >> 5, o = blockIdx.x & 31;
  const unsigned bb = (unsigned)batch<<16;
  __shared__ float2 lds[2][2048];
  __shared__ float tbs[600];
  __shared__ float red[8];
  float2 a[4];
  build_tbl(t, p0, p1, p2, p3, tbs);
  __syncthreads();
  // S1: gather via s1b; regs (j3,j4) = (g6,g7)
  #pragma unroll
  for (int s=0;s<4;s++) a[s] = st[bb | s1b(Ic(mapj<3,4>(t,s), o))];
  gate4<0>(a, TB(25)); gate4<1>(a, TB(24));                   // L1d1 g6,g7
  #pragma unroll
  for (int s=0;s<4;s++) lds[0][swz(mapj<3,4>(t,s))] = a[s];
  __syncthreads();
  // S2: regs (j5,j6) = (g8,g9)
  #pragma unroll
  for (int s=0;s<4;s++) a[s] = lds[0][swz(mapj<5,6>(t,s))];
  gate4<0>(a, TB(23)); gate4<1>(a, TB(22));                   // L1d1 g8,g9
  #pragma unroll
  for (int s=0;s<4;s++) lds[1][swz(mapj<5,6>(t,s))] = a[s];
  __syncthreads();
  // S3: regs (j7,j8) = (g10,g11)
  #pragma unroll
  for (int s=0;s<4;s++) a[s] = lds[1][swz(mapj<7,8>(t,s))];
  gate4<0>(a, TB(21));                                        // L1d1 g10 -> L1d1 done
  diag4<16,16, (1u<<10),(1u<<11)>(a, tbs, s1b(Ic(mapj<7,8>(t,0), o))); // D1 at pre-sigma1 index
  #pragma unroll
  for (int s=0;s<4;s++) lds[0][swz(mapj<7,8>(t,s))] = a[s];
  __syncthreads();
  // S4: regs (j10,j9) = (g15,g13); s1a folded into read -> full sigma1 now applied
  #pragma unroll
  for (int s=0;s<4;s++) a[s] = lds[0][swz(s1aperm(mapj<10,9>(t,s)))];
  gate4<0>(a, TB(32)); gate4<1>(a, TB(33));                   // L2d0 g15,g13
  #pragma unroll
  for (int s=0;s<4;s++) lds[1][swz(mapj<10,9>(t,s))] = a[s];
  __syncthreads();
  // S5: regs (j8,j6) = (g11,g9)
  #pragma unroll
  for (int s=0;s<4;s++) a[s] = lds[1][swz(mapj<8,6>(t,s))];
  gate4<0>(a, TB(34)); gate4<1>(a, TB(35));                   // L2d0 g11,g9
  #pragma unroll
  for (int s=0;s<4;s++) lds[0][swz(mapj<8,6>(t,s))] = a[s];
  __syncthreads();
  // S6: regs (j4,j2) = (g7,g5)
  #pragma unroll
  for (int s=0;s<4;s++) a[s] = lds[0][swz(mapj<4,2>(t,s))];
  gate4<0>(a, TB(36)); gate4<1>(a, TB(37));                   // L2d0 g7,g5
  #pragma unroll
  for (int s=0;s<4;s++) lds[1][swz(mapj<4,2>(t,s))] = a[s];
  __syncthreads();
  // S7: regs (j1,j0) = (g3,g1)
  #pragma unroll
  for (int s=0;s<4;s++) a[s] = lds[1][swz(mapj<1,0>(t,s))];
  gate4<0>(a, TB(38)); gate4<1>(a, TB(39));                   // L2d0 g3,g1 -> L2d0 done
  diag4<32,8, (1u<<3),(1u<<1)>(a, tbs, Ic(mapj<1,0>(t,0), o));// D2_0
  gate4<0>(a, TB(46)); gate4<1>(a, TB(47));                   // L2d1 g3,g1
  #pragma unroll
  for (int s=0;s<4;s++) lds[0][swz(mapj<1,0>(t,s))] = a[s];
  __syncthreads();
  // S8: regs (j2,j4) = (g5,g7)
  #pragma unroll
  for (int s=0;s<4;s++) a[s] = lds[0][swz(mapj<2,4>(t,s))];
  gate4<0>(a, TB(45)); gate4<1>(a, TB(44));                   // L2d1 g5,g7
  #pragma unroll
  for (int s=0;s<4;s++) lds[1][swz(mapj<2,4>(t,s))] = a[s];
  __syncthreads();
  // S9: regs (j6,j8) = (g9,g11)
  #pragma unroll
  for (int s=0;s<4;s++) a[s] = lds[1][swz(mapj<6,8>(t,s))];
  gate4<0>(a, TB(43)); gate4<1>(a, TB(42));                   // L2d1 g9,g11
  #pragma unroll
  for (int s=0;s<4;s++) lds[0][swz(mapj<6,8>(t,s))] = a[s];
  __syncthreads();
  // S10: regs (j9,j10) = (g13,g15)
  #pragma unroll
  for (int s=0;s<4;s++) a[s] = lds[0][swz(mapj<9,10>(t,s))];
  gate4<0>(a, TB(41)); gate4<1>(a, TB(40));                   // L2d1 g13,g15 -> done
  diag4<40,8, (1u<<13),(1u<<15)>(a, tbs, Ic(mapj<9,10>(t,0), o)); // D2_1
  { float2 tmp=a[2]; a[2]=a[3]; a[3]=tmp; }                   // sigma2: CNOT(g15->g13)
  gate4<1>(a, TB(48));                                        // L3d0 g15
  #pragma unroll
  for (int s=0;s<4;s++) lds[1][swz(mapj<9,10>(t,s))] = a[s];
  __syncthreads();
  // S11: regs (j8,j4) = (g11,g7); sigma2 remainder folded into read
  #pragma unroll
  for (int s=0;s<4;s++) a[s] = lds[1][swz(s2perm(mapj<8,4>(t,s)))];
  gate4<0>(a, TB(49)); gate4<1>(a, TB(50));                   // L3d0 g11,g7
  #pragma unroll
  for (int s=0;s<4;s++) lds[0][swz(mapj<8,4>(t,s))] = a[s];
  __syncthreads();
  // S12: regs (j1,j10) = (g3,g15)
  #pragma unroll
  for (int s=0;s<4;s++) a[s] = lds[0][swz(mapj<1,10>(t,s))];
  gate4<0>(a, TB(51));                                        // L3d0 g3 -> L3d0 done
  diag4<48,4, (1u<<3),(1u<<15)>(a, tbs, Ic(mapj<1,10>(t,0), o)); // D3_0
  gate4<0>(a, TB(55)); gate4<1>(a, TB(52));                   // L3d1 g3,g15
  #pragma unroll
  for (int s=0;s<4;s++) lds[1][swz(mapj<1,10>(t,s))] = a[s];
  __syncthreads();
  // S13: regs (j4,j8) = (g7,g11)
  #pragma unroll
  for (int s=0;s<4;s++) a[s] = lds[1][swz(mapj<4,8>(t,s))];
  gate4<0>(a, TB(54)); gate4<1>(a, TB(53));                   // L3d1 g7,g11 -> done
  diag4<52,4, (1u<<7),(1u<<11)>(a, tbs, Ic(mapj<4,8>(t,0), o)); // D3_1
  #pragma unroll
  for (int s=0;s<4;s++) lds[0][swz(mapj<4,8>(t,s))] = a[s];
  __syncthreads();
  // S14: regs (j4,j10) = (g7,g15); sigma3 folded into read
  #pragma unroll
  for (int s=0;s<4;s++) a[s] = lds[0][swz(s3perm(mapj<4,10>(t,s)))];
  gate4<0>(a, TB(57)); gate4<1>(a, TB(56));                   // L4d0 g7,g15
  diag4<56,2, (1u<<7),(1u<<15)>(a, tbs, Ic(mapj<4,10>(t,0), o)); // D4_0
  gate4<1>(a, TB(58));                                        // L4d1 g15
  // sigma4, D4_1, L4d1(g7) dropped: invariant for the g15 marginal.
  float s = 0.f;
  #pragma unroll
  for (int r=0;r<4;r++){
    float w = a[r].x*a[r].x + a[r].y*a[r].y;
    s += (r & 2) ? -w : w;
  }
  #pragma unroll
  for (int off=32; off>0; off>>=1) s += __shfl_down(s, off);
  if ((t & 63) == 0) red[t>>6] = s;
  __syncthreads();
  if (t == 0){
    float tot = 0.f;
    #pragma unroll
    for (int w=0; w<8; w++) tot += red[w];
    atomicAdd(out + batch, tot);
  }
}

extern "C" void kernel_launch(void* const* d_in, const int* in_sizes, int n_in,
                              void* d_out, int out_size, void* d_ws, size_t ws_size,
                              hipStream_t stream) {
  const float* xre = (const float*)d_in[0];
  const float* xim = (const float*)d_in[1];
  const float* p0  = (const float*)d_in[2];
  const float* p1  = (const float*)d_in[3];
  const float* p2  = (const float*)d_in[4];
  const float* p3  = (const float*)d_in[5];
  float* out = (float*)d_out;
  float2* st = (float2*)d_ws;                           // 8 MB state

  k_p1<<<512, 512, 0, stream>>>(xre, xim, p0, p1, p2, p3, st, out);
  k_p2<<<512, 512, 0, stream>>>(p0, p1, p2, p3, st);
  k_p4<<<512, 512, 0, stream>>>(p0, p1, p2, p3, st, out);
}